// Round 3
// baseline (1332.470 us; speedup 1.0000x reference)
//
#include <hip/hip_runtime.h>

#define D 64
#define SCAN_BLOCK 256

__global__ void counti_kernel(const int* __restrict__ dst, int* __restrict__ cnti, int E) {
    int i = blockIdx.x * blockDim.x + threadIdx.x;
    int stride = gridDim.x * blockDim.x;
    for (; i < E; i += stride)
        atomicAdd(&cnti[dst[i]], 1);
}

// Block-wise inclusive scan (Hillis-Steele) -> exclusive per-element + block sums
__global__ void scan1_kernel(const int* __restrict__ cnti, int* __restrict__ excl,
                             int* __restrict__ bsum, int N) {
    __shared__ int tmp[SCAN_BLOCK];
    int gid = blockIdx.x * SCAN_BLOCK + threadIdx.x;
    int v = (gid < N) ? cnti[gid] : 0;
    tmp[threadIdx.x] = v;
    __syncthreads();
    for (int ofs = 1; ofs < SCAN_BLOCK; ofs <<= 1) {
        int t = (threadIdx.x >= ofs) ? tmp[threadIdx.x - ofs] : 0;
        __syncthreads();
        tmp[threadIdx.x] += t;
        __syncthreads();
    }
    if (gid < N) excl[gid] = tmp[threadIdx.x] - v;
    if (threadIdx.x == SCAN_BLOCK - 1) bsum[blockIdx.x] = tmp[SCAN_BLOCK - 1];
}

__global__ void scan2_kernel(int* __restrict__ bsum, int* __restrict__ bofs, int nb) {
    __shared__ int tmp[SCAN_BLOCK];
    int v = (threadIdx.x < nb) ? bsum[threadIdx.x] : 0;
    tmp[threadIdx.x] = v;
    __syncthreads();
    for (int ofs = 1; ofs < SCAN_BLOCK; ofs <<= 1) {
        int t = (threadIdx.x >= ofs) ? tmp[threadIdx.x - ofs] : 0;
        __syncthreads();
        tmp[threadIdx.x] += t;
        __syncthreads();
    }
    if (threadIdx.x < nb) bofs[threadIdx.x] = tmp[threadIdx.x] - v;
}

__global__ void scan3_kernel(const int* __restrict__ excl, const int* __restrict__ bofs,
                             int* __restrict__ off, int* __restrict__ cur, int N) {
    int gid = blockIdx.x * SCAN_BLOCK + threadIdx.x;
    if (gid < N) {
        int o = excl[gid] + bofs[blockIdx.x];
        off[gid] = o;
        cur[gid] = o;
    }
}

__global__ void fill_kernel(const int* __restrict__ src, const int* __restrict__ dst,
                            int* __restrict__ cur, int* __restrict__ eidx, int E) {
    int i = blockIdx.x * blockDim.x + threadIdx.x;
    int stride = gridDim.x * blockDim.x;
    for (; i < E; i += stride) {
        int pos = atomicAdd(&cur[dst[i]], 1);
        eidx[pos] = src[i];
    }
}

// Gather-mean: 64 lanes per node = 4 edge-subgroups x 16 dim-lanes.
// 4 edges in flight per wave-step (x2 unroll = 8 rows outstanding), then
// __shfl_xor reduce over the 4 subgroups.
__global__ void agg_kernel(const float* __restrict__ xin, const int* __restrict__ eidx,
                           const int* __restrict__ off, const int* __restrict__ cnti,
                           float* __restrict__ mean, int N) {
    int gid = blockIdx.x * blockDim.x + threadIdx.x;
    int node = gid >> 6;
    if (node >= N) return;
    int tid = threadIdx.x;
    int g = (tid >> 4) & 3;      // edge subgroup 0..3
    int lane16 = tid & 15;       // 16B dim chunk
    int start = off[node];
    int deg = cnti[node];
    int end = start + deg;
    float4 acc = make_float4(0.f, 0.f, 0.f, 0.f);
    int i = start + g;
    for (; i + 4 < end; i += 8) {            // two edges per subgroup in flight
        int s0 = eidx[i], s1 = eidx[i + 4];
        float4 v0 = *reinterpret_cast<const float4*>(xin + (size_t)s0 * D + lane16 * 4);
        float4 v1 = *reinterpret_cast<const float4*>(xin + (size_t)s1 * D + lane16 * 4);
        acc.x += v0.x + v1.x; acc.y += v0.y + v1.y;
        acc.z += v0.z + v1.z; acc.w += v0.w + v1.w;
    }
    if (i < end) {
        int s0 = eidx[i];
        float4 v0 = *reinterpret_cast<const float4*>(xin + (size_t)s0 * D + lane16 * 4);
        acc.x += v0.x; acc.y += v0.y; acc.z += v0.z; acc.w += v0.w;
    }
    // reduce across the 4 subgroups (lanes ^16, ^32)
    acc.x += __shfl_xor(acc.x, 16); acc.y += __shfl_xor(acc.y, 16);
    acc.z += __shfl_xor(acc.z, 16); acc.w += __shfl_xor(acc.w, 16);
    acc.x += __shfl_xor(acc.x, 32); acc.y += __shfl_xor(acc.y, 32);
    acc.z += __shfl_xor(acc.z, 32); acc.w += __shfl_xor(acc.w, 32);
    if (g == 0) {
        float r = 1.0f / fmaxf((float)deg, 1.0f);
        acc.x *= r; acc.y *= r; acc.z *= r; acc.w *= r;
        *reinterpret_cast<float4*>(mean + (size_t)node * D + lane16 * 4) = acc;
    }
}

// Thread = node. x-row / mean-row in VGPRs; W & bias read at wave-uniform
// addresses -> scalar loads (s_load) feeding v_fmac's SGPR operand. No LDS.
__global__ void layer_kernel(const float* __restrict__ xin,
                             const float* __restrict__ mean,
                             const float* __restrict__ Wl,
                             const float* __restrict__ Wr,
                             const float* __restrict__ bias,
                             float* __restrict__ out,
                             int do_relu, int N) {
    int node = blockIdx.x * blockDim.x + threadIdx.x;
    if (node >= N) return;
    float xr[D], mr[D];
    const float* xp = xin + (size_t)node * D;
    const float* mp = mean + (size_t)node * D;
#pragma unroll
    for (int c = 0; c < D / 4; ++c) {
        float4 xv = *reinterpret_cast<const float4*>(xp + c * 4);
        float4 mv = *reinterpret_cast<const float4*>(mp + c * 4);
        xr[c * 4 + 0] = xv.x; xr[c * 4 + 1] = xv.y; xr[c * 4 + 2] = xv.z; xr[c * 4 + 3] = xv.w;
        mr[c * 4 + 0] = mv.x; mr[c * 4 + 1] = mv.y; mr[c * 4 + 2] = mv.z; mr[c * 4 + 3] = mv.w;
    }
    float* op = out + (size_t)node * D;
    for (int d4 = 0; d4 < D / 4; ++d4) {     // dynamic outer loop keeps code size sane
        float o[4];
#pragma unroll
        for (int j = 0; j < 4; ++j) {
            int d = d4 * 4 + j;
            const float* wl = Wl + d * D;    // uniform address -> s_load
            const float* wr = Wr + d * D;
            float a = bias[d];
#pragma unroll
            for (int k = 0; k < D; ++k)
                a = fmaf(mr[k], wl[k], fmaf(xr[k], wr[k], a));
            if (do_relu) a = fmaxf(a, 0.0f);
            o[j] = a;
        }
        *reinterpret_cast<float4*>(op + d4 * 4) = make_float4(o[0], o[1], o[2], o[3]);
    }
}

extern "C" void kernel_launch(void* const* d_in, const int* in_sizes, int n_in,
                              void* d_out, int out_size, void* d_ws, size_t ws_size,
                              hipStream_t stream) {
    const float* x   = (const float*)d_in[0];
    const int*   ei  = (const int*)d_in[1];
    const float* Wl1 = (const float*)d_in[2];
    const float* Wr1 = (const float*)d_in[3];
    const float* b1  = (const float*)d_in[4];
    const float* Wl2 = (const float*)d_in[5];
    const float* Wr2 = (const float*)d_in[6];
    const float* b2  = (const float*)d_in[7];

    int N_ = in_sizes[0] / D;   // 50000
    int E_ = in_sizes[1] / 2;   // 800000
    const int* src = ei;
    const int* dst = ei + E_;

    int*   cnti = (int*)d_ws;                       // [N]
    int*   excl = cnti + N_;                        // [N]
    int*   cur  = excl + N_;                        // [N]
    int*   off  = cur + N_;                         // [N]
    int*   bsum = off + N_;                         // [256]
    int*   bofs = bsum + 256;                       // [256]
    int*   eidx = bofs + 256;                       // [E]
    float* mean = (float*)(eidx + E_);              // [N, D]
    float* h    = (float*)d_out;                    // layer-1 output in d_out (in-place safe)
    float* outp = (float*)d_out;

    int nbScan = (N_ + SCAN_BLOCK - 1) / SCAN_BLOCK;

    hipMemsetAsync(cnti, 0, (size_t)N_ * sizeof(int), stream);
    counti_kernel<<<2048, 256, 0, stream>>>(dst, cnti, E_);

    scan1_kernel<<<nbScan, SCAN_BLOCK, 0, stream>>>(cnti, excl, bsum, N_);
    scan2_kernel<<<1, SCAN_BLOCK, 0, stream>>>(bsum, bofs, nbScan);
    scan3_kernel<<<nbScan, SCAN_BLOCK, 0, stream>>>(excl, bofs, off, cur, N_);
    fill_kernel<<<2048, 256, 0, stream>>>(src, dst, cur, eidx, E_);

    int aggBlocks = (N_ * 64 + 255) / 256;           // 64 lanes/node
    int layerBlocks = (N_ + 255) / 256;

    // Layer 1
    agg_kernel<<<aggBlocks, 256, 0, stream>>>(x, eidx, off, cnti, mean, N_);
    layer_kernel<<<layerBlocks, 256, 0, stream>>>(x, mean, Wl1, Wr1, b1, h, 1, N_);

    // Layer 2
    agg_kernel<<<aggBlocks, 256, 0, stream>>>(h, eidx, off, cnti, mean, N_);
    layer_kernel<<<layerBlocks, 256, 0, stream>>>(h, mean, Wl2, Wr2, b2, outp, 0, N_);
}